// Round 22
// baseline (220.868 us; speedup 1.0000x reference)
//
#include <hip/hip_runtime.h>
#include <math.h>

#define N_NODES 50000
#define N_EDGES 800000
#define IN_FT   512
#define H_FT    256
#define OUT_FT  40
#define NBLK    782                          // ceil(50000/64)
#define NROWS   (NBLK * 64)                  // 50048
#define CAP     64                           // slots per node (max deg <= 64)
#define NB_ZERO ((N_NODES + 255) / 256)      // 196
#define NB_SCAT ((N_EDGES + 255) / 256)      // 3125
#define NB_CVTX (NBLK * 8)                   // 6256

typedef __attribute__((ext_vector_type(8))) short short8;            // 8 x bf16
typedef __attribute__((ext_vector_type(8))) unsigned short ushort8;  // 8 x bf16
typedef __attribute__((ext_vector_type(4))) float f32x4;

__device__ __forceinline__ unsigned short f2b(float f) {    // f32 -> bf16 RNE
    unsigned int u = __float_as_uint(f);
    unsigned int r = (u + 0x7FFFu + ((u >> 16) & 1u)) >> 16;
    return (unsigned short)r;
}
__device__ __forceinline__ float b2f(unsigned short h) {
    return __uint_as_float(((unsigned int)h) << 16);
}
__device__ __forceinline__ short8 cvt8(float4 a, float4 b) {
    short8 r;
    r[0] = (short)f2b(a.x); r[1] = (short)f2b(a.y);
    r[2] = (short)f2b(a.z); r[3] = (short)f2b(a.w);
    r[4] = (short)f2b(b.x); r[5] = (short)f2b(b.y);
    r[6] = (short)f2b(b.z); r[7] = (short)f2b(b.w);
    return r;
}

// ===== prepA: zero cnt (196) + cvtxb (6256) + W1F (16) + W2F (3) ============
__global__ __launch_bounds__(256) void prepA_k(const float* __restrict__ X,
                                               const float* __restrict__ W1,
                                               const float* __restrict__ W2,
                                               int* __restrict__ cnt,
                                               unsigned short* __restrict__ XB,
                                               unsigned short* __restrict__ W1F,
                                               unsigned short* __restrict__ W2F) {
    __shared__ unsigned short lt[64][72];
    const int b = blockIdx.x;
    const int t = threadIdx.x;

    if (b < NB_ZERO) {
        const int i = b * 256 + t;
        if (i < N_NODES) cnt[i] = 0;
        return;
    } else if (b < NB_ZERO + NB_CVTX) {
        // ---- x -> xb fragment-major bf16 (one kt-tile per block) ----
        const int idx = b - NB_ZERO;
        const int blk = idx >> 3;
        const int kt  = idx & 7;
        const int m0  = blk * 64;
        const int rrow = t >> 2, rpart = t & 3;      // read: 4 thr/row, 16 f32
        const int fr = t & 15, fq = (t >> 4) & 3, mi = (t >> 6) & 3;
        unsigned short* outp = XB + (size_t)blk * 32768;
        const int arow = m0 + rrow;

        short8 s0, s1;
        if (arow < N_NODES) {
            const float* xp = X + (size_t)arow * IN_FT + kt * 64 + rpart * 16;
            const float4 v0 = *(const float4*)(xp + 0);
            const float4 v1 = *(const float4*)(xp + 4);
            const float4 v2 = *(const float4*)(xp + 8);
            const float4 v3 = *(const float4*)(xp + 12);
            s0 = cvt8(v0, v1); s1 = cvt8(v2, v3);
        } else {
            short8 z = {}; s0 = z; s1 = z;
        }
        *(short8*)&lt[rrow][rpart * 16 + 0] = s0;
        *(short8*)&lt[rrow][rpart * 16 + 8] = s1;
        __syncthreads();
        #pragma unroll
        for (int ks = 0; ks < 2; ++ks) {
            const short8 v = *(const short8*)&lt[mi * 16 + fr][ks * 32 + fq * 8];
            *(short8*)(outp + (((kt * 2 + ks) * 4 + mi) * 4 + fq) * 128 + fr * 8) = v;
        }
        return;
    } else if (b < NB_ZERO + NB_CVTX + 16) {
        // ---- W1F[nblk16][kt8][ks2][fq4][fr16][8] ----
        const int nblk = b - NB_ZERO - NB_CVTX;
        const int fr = t & 15, fq = (t >> 4) & 3, ks = (t >> 6) & 1, kh = t >> 7;
        const int n = nblk * 16 + fr;
        #pragma unroll
        for (int k4 = 0; k4 < 4; ++k4) {
            const int kt = k4 * 2 + kh;
            const int k0 = kt * 64 + ks * 32 + fq * 8;
            unsigned short o[8];
            #pragma unroll
            for (int j = 0; j < 8; ++j) o[j] = f2b(W1[(size_t)(k0 + j) * H_FT + n]);
            *(short8*)(W1F + ((((size_t)nblk * 8 + kt) * 2 + ks) * 4 + fq) * 128 + fr * 8)
                = *(const short8*)o;
        }
    } else {
        // ---- W2F[nblk3][ks8][fq4][fr16][8] (cols 40..47 zero) ----
        const int nblk = b - NB_ZERO - NB_CVTX - 16;
        const int fr = t & 15, fq = (t >> 4) & 3, ksq = (t >> 6) & 3;
        const int n = nblk * 16 + fr;
        #pragma unroll
        for (int i = 0; i < 2; ++i) {
            const int ks = i * 4 + ksq;
            const int k0 = ks * 32 + fq * 8;
            unsigned short o[8];
            #pragma unroll
            for (int j = 0; j < 8; ++j)
                o[j] = (n < OUT_FT) ? f2b(W2[(size_t)(k0 + j) * OUT_FT + n]) : 0;
            *(short8*)(W2F + (((size_t)nblk * 8 + ks) * 4 + fq) * 128 + fr * 8)
                = *(const short8*)o;
        }
    }
}

// ===== prepB: scatter (3128 slots) : gemm1 (782), 4:1 interleave ============
// Small 8.4KB LDS (4-pass epilogue) so scatter blocks keep high occupancy.
__global__ __launch_bounds__(256) void prepB_k(const int* __restrict__ src,
                                               const int* __restrict__ dst,
                                               const float* __restrict__ w,
                                               int* __restrict__ cnt,
                                               unsigned int* __restrict__ pk,
                                               const unsigned short* __restrict__ XB,
                                               const unsigned short* __restrict__ W1F,
                                               const float* __restrict__ bias,
                                               unsigned short* __restrict__ C) {
    __shared__ unsigned short ldsS[16][264];         // 8.4 KB (epilogue, 4 passes)
    const int b = blockIdx.x;
    const int t = threadIdx.x;
    const int q = b / 5, r = b - q * 5;

    if (r < 4) {
        // ---- edge scatter (block-equivalent si = q*4+r) ----
        const int e = (q * 4 + r) * 256 + t;
        if (e < N_EDGES) {
            const int d = dst[e];
            const int pos = atomicAdd(&cnt[d], 1);
            if (pos < CAP) {
                pk[(size_t)d * CAP + pos] =
                    ((unsigned int)f2b(w[e]) << 16) | (unsigned int)src[e];
            }
        }
        return;
    }

    // ---- gemm1: LDS-free MFMA compute, coalesced fragment loads ----
    const int bid  = q;                              // 0..781
    const int lane = t & 63;
    const int wid  = t >> 6;
    const int m0   = bid * 64;
    const int fr   = lane & 15;
    const int fq   = lane >> 4;

    f32x4 acc[4][4] = {};
    const unsigned short* ap = XB + (size_t)bid * 32768 + lane * 8;
    const unsigned short* bp = W1F + ((size_t)wid * 4 * 8 * 2 * 64 + lane) * 8;

    #pragma unroll 2
    for (int kt = 0; kt < 8; ++kt) {
        short8 afr[8], bfr[8];
        #pragma unroll
        for (int f = 0; f < 8; ++f) {                // f = ks*4+mi
            const int mi = f & 3, ks = f >> 2;
            afr[f] = *(const short8*)(ap + ((kt * 2 + ks) * 4 + mi) * 512);
        }
        #pragma unroll
        for (int f = 0; f < 8; ++f) {                // f = ni*2+ks
            const int ni = f >> 1, ks = f & 1;
            bfr[f] = *(const short8*)(bp + ((size_t)(ni * 8 + kt) * 2 + ks) * 512);
        }
        #pragma unroll
        for (int ks = 0; ks < 2; ++ks)
            #pragma unroll
            for (int mi = 0; mi < 4; ++mi)
                #pragma unroll
                for (int ni = 0; ni < 4; ++ni)
                    acc[mi][ni] = __builtin_amdgcn_mfma_f32_16x16x32_bf16(
                        afr[ks * 4 + mi], bfr[ni * 2 + ks], acc[mi][ni], 0, 0, 0);
    }

    // ---- epilogue: 4 passes of 16 rows through 8.4KB LDS ----
    const int srow  = t >> 4;                        // store: 16 rows, 16 thr/row
    const int spart = t & 15;                        // 2x short8 = 32B per thread
    #pragma unroll 1
    for (int mi = 0; mi < 4; ++mi) {
        #pragma unroll
        for (int ni = 0; ni < 4; ++ni) {
            const int col = wid * 64 + ni * 16 + fr;
            const float bv = bias[col];
            #pragma unroll
            for (int j = 0; j < 4; ++j)
                ldsS[fq * 4 + j][col] = f2b(acc[mi][ni][j] + bv);
        }
        __syncthreads();
        unsigned short* cp = C + (size_t)(m0 + mi * 16 + srow) * H_FT;
        #pragma unroll
        for (int i = 0; i < 2; ++i) {
            const int c0 = spart * 8 + i * 128;
            *(short8*)(cp + c0) = *(const short8*)&ldsS[srow][c0];
        }
        __syncthreads();
    }
}

// ========== SpMM1 gather: 8 edges in flight (4-deep per 32-lane half) =======
__global__ __launch_bounds__(256) void spmm1_g(const int* __restrict__ cnt,
                                               const unsigned int* __restrict__ pk,
                                               const unsigned short* __restrict__ sup,
                                               unsigned short* __restrict__ hout) {
    const int m = blockIdx.x * 4 + (threadIdx.x >> 6);
    const int lane = threadIdx.x & 63;
    const int half = lane >> 5;                  // 0: even edges, 1: odd edges
    const int fl   = lane & 31;                  // feature lane: 8 bf16 each
    float aA[8] = {}, aB[8] = {}, aC[8] = {}, aD[8] = {};
    const int e = min(cnt[m], CAP);
    const unsigned int* base = pk + (size_t)m * CAP;
    int i = half;
    for (; i + 6 < e; i += 8) {                  // 4 edges per half in flight
        const unsigned int u0 = base[i], u1 = base[i + 2], u2 = base[i + 4], u3 = base[i + 6];
        const ushort8 v0 = *(const ushort8*)(sup + (size_t)(u0 & 0xFFFF) * H_FT + fl * 8);
        const ushort8 v1 = *(const ushort8*)(sup + (size_t)(u1 & 0xFFFF) * H_FT + fl * 8);
        const ushort8 v2 = *(const ushort8*)(sup + (size_t)(u2 & 0xFFFF) * H_FT + fl * 8);
        const ushort8 v3 = *(const ushort8*)(sup + (size_t)(u3 & 0xFFFF) * H_FT + fl * 8);
        const float w0 = b2f((unsigned short)(u0 >> 16));
        const float w1 = b2f((unsigned short)(u1 >> 16));
        const float w2 = b2f((unsigned short)(u2 >> 16));
        const float w3 = b2f((unsigned short)(u3 >> 16));
        #pragma unroll
        for (int j = 0; j < 8; ++j) {
            aA[j] += b2f(v0[j]) * w0;
            aB[j] += b2f(v1[j]) * w1;
            aC[j] += b2f(v2[j]) * w2;
            aD[j] += b2f(v3[j]) * w3;
        }
    }
    for (; i + 2 < e; i += 4) {                  // 2 edges per half
        const unsigned int u0 = base[i], u1 = base[i + 2];
        const ushort8 v0 = *(const ushort8*)(sup + (size_t)(u0 & 0xFFFF) * H_FT + fl * 8);
        const ushort8 v1 = *(const ushort8*)(sup + (size_t)(u1 & 0xFFFF) * H_FT + fl * 8);
        const float w0 = b2f((unsigned short)(u0 >> 16));
        const float w1 = b2f((unsigned short)(u1 >> 16));
        #pragma unroll
        for (int j = 0; j < 8; ++j) {
            aA[j] += b2f(v0[j]) * w0;
            aB[j] += b2f(v1[j]) * w1;
        }
    }
    for (; i < e; i += 2) {
        const unsigned int u = base[i];
        const ushort8 v = *(const ushort8*)(sup + (size_t)(u & 0xFFFF) * H_FT + fl * 8);
        const float w = b2f((unsigned short)(u >> 16));
        #pragma unroll
        for (int j = 0; j < 8; ++j) aA[j] += b2f(v[j]) * w;
    }
    ushort8 r;
    #pragma unroll
    for (int j = 0; j < 8; ++j) {
        float a = (aA[j] + aB[j]) + (aC[j] + aD[j]);
        a += __shfl_xor(a, 32);                  // even-half + odd-half
        r[j] = f2b(fmaxf(a, 0.f));
    }
    if (half == 0)
        *(ushort8*)(hout + (size_t)m * H_FT + fl * 8) = r;
}

// ======= GEMM2 (MFMA): sup2[M,40] = hb[M,256] @ W2F + b2  (bf16 out) ========
__global__ __launch_bounds__(256) void gemm2_mfma(const unsigned short* __restrict__ hb,
                                                  const unsigned short* __restrict__ W2F,
                                                  const float* __restrict__ b2,
                                                  unsigned short* __restrict__ sup2) {
    const int t = threadIdx.x;
    const int lane = t & 63;
    const int wid = t >> 6;
    const int fr = lane & 15;
    const int fq = lane >> 4;
    const int row = blockIdx.x * 64 + wid * 16 + fr;
    const int rl = (row < N_NODES) ? row : (N_NODES - 1);

    f32x4 acc[3] = {};
    const unsigned short* ap = hb + (size_t)rl * H_FT + fq * 8;
    #pragma unroll
    for (int ks = 0; ks < 8; ++ks) {
        const short8 a = *(const short8*)(ap + ks * 32);
        #pragma unroll
        for (int ni = 0; ni < 3; ++ni) {
            const short8 b = *(const short8*)(W2F +
                (((size_t)ni * 8 + ks) * 64 + lane) * 8);
            acc[ni] = __builtin_amdgcn_mfma_f32_16x16x32_bf16(a, b, acc[ni], 0, 0, 0);
        }
    }
    #pragma unroll
    for (int ni = 0; ni < 3; ++ni) {
        const int col = ni * 16 + fr;
        if (col >= OUT_FT) continue;
        const float bv = b2[col];
        #pragma unroll
        for (int j = 0; j < 4; ++j) {
            const int r = blockIdx.x * 64 + wid * 16 + fq * 4 + j;
            if (r < N_NODES)
                sup2[(size_t)r * OUT_FT + col] = f2b(acc[ni][j] + bv);
        }
    }
}

// ===== SpMM2 + relu + log_softmax fused (bf16 gather, 8-deep) ===============
__global__ __launch_bounds__(256) void spmm2lsm_k(const int* __restrict__ cnt,
                                                  const unsigned int* __restrict__ pk,
                                                  const unsigned short* __restrict__ sup2,
                                                  float* __restrict__ out) {
    const int m = blockIdx.x * 4 + (threadIdx.x >> 6);
    const int lane = threadIdx.x & 63;
    const int f = (lane < OUT_FT) ? lane : 0;
    float a0 = 0.f, a1 = 0.f, a2 = 0.f, a3 = 0.f;
    const int e = min(cnt[m], CAP);
    const unsigned int* base = pk + (size_t)m * CAP;
    int i = 0;
    for (; i + 8 <= e; i += 8) {
        const unsigned int u0 = base[i],     u1 = base[i + 1], u2 = base[i + 2], u3 = base[i + 3];
        const unsigned int u4 = base[i + 4], u5 = base[i + 5], u6 = base[i + 6], u7 = base[i + 7];
        const float v0 = b2f(sup2[(size_t)(u0 & 0xFFFF) * OUT_FT + f]);
        const float v1 = b2f(sup2[(size_t)(u1 & 0xFFFF) * OUT_FT + f]);
        const float v2 = b2f(sup2[(size_t)(u2 & 0xFFFF) * OUT_FT + f]);
        const float v3 = b2f(sup2[(size_t)(u3 & 0xFFFF) * OUT_FT + f]);
        const float v4 = b2f(sup2[(size_t)(u4 & 0xFFFF) * OUT_FT + f]);
        const float v5 = b2f(sup2[(size_t)(u5 & 0xFFFF) * OUT_FT + f]);
        const float v6 = b2f(sup2[(size_t)(u6 & 0xFFFF) * OUT_FT + f]);
        const float v7 = b2f(sup2[(size_t)(u7 & 0xFFFF) * OUT_FT + f]);
        a0 += v0 * b2f((unsigned short)(u0 >> 16));
        a1 += v1 * b2f((unsigned short)(u1 >> 16));
        a2 += v2 * b2f((unsigned short)(u2 >> 16));
        a3 += v3 * b2f((unsigned short)(u3 >> 16));
        a0 += v4 * b2f((unsigned short)(u4 >> 16));
        a1 += v5 * b2f((unsigned short)(u5 >> 16));
        a2 += v6 * b2f((unsigned short)(u6 >> 16));
        a3 += v7 * b2f((unsigned short)(u7 >> 16));
    }
    for (; i + 4 <= e; i += 4) {
        const unsigned int u0 = base[i], u1 = base[i + 1], u2 = base[i + 2], u3 = base[i + 3];
        a0 += b2f(sup2[(size_t)(u0 & 0xFFFF) * OUT_FT + f]) * b2f((unsigned short)(u0 >> 16));
        a1 += b2f(sup2[(size_t)(u1 & 0xFFFF) * OUT_FT + f]) * b2f((unsigned short)(u1 >> 16));
        a2 += b2f(sup2[(size_t)(u2 & 0xFFFF) * OUT_FT + f]) * b2f((unsigned short)(u2 >> 16));
        a3 += b2f(sup2[(size_t)(u3 & 0xFFFF) * OUT_FT + f]) * b2f((unsigned short)(u3 >> 16));
    }
    for (; i < e; ++i) {
        const unsigned int u = base[i];
        a0 += b2f(sup2[(size_t)(u & 0xFFFF) * OUT_FT + f]) * b2f((unsigned short)(u >> 16));
    }
    const float acc = (a0 + a1) + (a2 + a3);
    const bool act = (lane < OUT_FT);
    float r = act ? fmaxf(acc, 0.f) : 0.f;
    float mx = act ? r : -INFINITY;
    #pragma unroll
    for (int o = 32; o; o >>= 1) mx = fmaxf(mx, __shfl_xor(mx, o));
    float ex = act ? expf(r - mx) : 0.f;
    #pragma unroll
    for (int o = 32; o; o >>= 1) ex += __shfl_xor(ex, o);
    if (act) out[(size_t)m * OUT_FT + lane] = r - mx - logf(ex);
}

extern "C" void kernel_launch(void* const* d_in, const int* in_sizes, int n_in,
                              void* d_out, int out_size, void* d_ws, size_t ws_size,
                              hipStream_t stream) {
    const float* x    = (const float*)d_in[0];
    const int*   esrc = (const int*)  d_in[1];
    const int*   edst = (const int*)  d_in[2];
    const float* ew   = (const float*)d_in[3];
    const float* W1   = (const float*)d_in[4];
    const float* b1   = (const float*)d_in[5];
    const float* W2   = (const float*)d_in[6];
    const float* b2   = (const float*)d_in[7];
    float* out = (float*)d_out;

    // ---- workspace layout ----
    char* p = (char*)d_ws;
    int*  cnt    = (int*)p;               p += ((N_NODES * 4 + 255) & ~255);
    unsigned int* pk = (unsigned int*)p;  p += (size_t)N_NODES * CAP * 4;
    unsigned short* w1f  = (unsigned short*)p;  p += (size_t)H_FT * IN_FT * 2;
    unsigned short* w2f  = (unsigned short*)p;  p += (size_t)48 * H_FT * 2;
    unsigned short* sup1 = (unsigned short*)p;  p += (size_t)NROWS * H_FT * 2;
    unsigned short* hb   = (unsigned short*)p;  p += (size_t)N_NODES * H_FT * 2;
    unsigned short* sup2 = (unsigned short*)p;  p += ((size_t)N_NODES * OUT_FT * 2 + 255) & ~255;
    unsigned short* xb   = (unsigned short*)p;  p += (size_t)NBLK * 32768 * 2;

    // prepA: {zero | cvtxb | W-packs};  prepB: {scatter : gemm1, 4:1}
    prepA_k<<<NB_ZERO + NB_CVTX + 16 + 3, 256, 0, stream>>>(
        x, W1, W2, cnt, xb, w1f, w2f);
    prepB_k<<<NBLK * 5, 256, 0, stream>>>(
        esrc, edst, ew, cnt, pk, xb, w1f, b1, sup1);

    // layer 1 aggregate
    spmm1_g<<<N_NODES / 4, 256, 0, stream>>>(cnt, pk, sup1, hb);

    // layer 2 (+ fused relu + log_softmax)
    gemm2_mfma<<<(N_NODES + 63) / 64, 256, 0, stream>>>(hb, w2f, b2, sup2);
    spmm2lsm_k<<<N_NODES / 4, 256, 0, stream>>>(cnt, pk, sup2, out);
}

// Round 23
// 176.829 us; speedup vs baseline: 1.2490x; 1.2490x over previous
//
#include <hip/hip_runtime.h>
#include <math.h>

#define N_NODES 50000
#define N_EDGES 800000
#define IN_FT   512
#define H_FT    256
#define OUT_FT  40
#define NBLK    782                          // ceil(50000/64)
#define NROWS   (NBLK * 64)                  // 50048
#define CAP     64                           // slots per node (max deg <= 64)
#define NB_ZERO ((N_NODES + 255) / 256)      // 196
#define NB_SCAT ((N_EDGES + 255) / 256)      // 3125
#define NB_CVTX (NBLK * 8)                   // 6256

typedef __attribute__((ext_vector_type(8))) short short8;            // 8 x bf16
typedef __attribute__((ext_vector_type(8))) unsigned short ushort8;  // 8 x bf16
typedef __attribute__((ext_vector_type(4))) float f32x4;

__device__ __forceinline__ unsigned short f2b(float f) {    // f32 -> bf16 RNE
    unsigned int u = __float_as_uint(f);
    unsigned int r = (u + 0x7FFFu + ((u >> 16) & 1u)) >> 16;
    return (unsigned short)r;
}
__device__ __forceinline__ float b2f(unsigned short h) {
    return __uint_as_float(((unsigned int)h) << 16);
}
__device__ __forceinline__ short8 cvt8(float4 a, float4 b) {
    short8 r;
    r[0] = (short)f2b(a.x); r[1] = (short)f2b(a.y);
    r[2] = (short)f2b(a.z); r[3] = (short)f2b(a.w);
    r[4] = (short)f2b(b.x); r[5] = (short)f2b(b.y);
    r[6] = (short)f2b(b.z); r[7] = (short)f2b(b.w);
    return r;
}

// ===== prepA: zero cnt (196) + cvtxb (6256) + W1F (16) + W2F (3) ============
__global__ __launch_bounds__(256) void prepA_k(const float* __restrict__ X,
                                               const float* __restrict__ W1,
                                               const float* __restrict__ W2,
                                               int* __restrict__ cnt,
                                               unsigned short* __restrict__ XB,
                                               unsigned short* __restrict__ W1F,
                                               unsigned short* __restrict__ W2F) {
    __shared__ unsigned short lt[64][72];
    const int b = blockIdx.x;
    const int t = threadIdx.x;

    if (b < NB_ZERO) {
        const int i = b * 256 + t;
        if (i < N_NODES) cnt[i] = 0;
        return;
    } else if (b < NB_ZERO + NB_CVTX) {
        // ---- x -> xb fragment-major bf16 (one kt-tile per block) ----
        const int idx = b - NB_ZERO;
        const int blk = idx >> 3;
        const int kt  = idx & 7;
        const int m0  = blk * 64;
        const int rrow = t >> 2, rpart = t & 3;      // read: 4 thr/row, 16 f32
        const int fr = t & 15, fq = (t >> 4) & 3, mi = (t >> 6) & 3;
        unsigned short* outp = XB + (size_t)blk * 32768;
        const int arow = m0 + rrow;

        short8 s0, s1;
        if (arow < N_NODES) {
            const float* xp = X + (size_t)arow * IN_FT + kt * 64 + rpart * 16;
            const float4 v0 = *(const float4*)(xp + 0);
            const float4 v1 = *(const float4*)(xp + 4);
            const float4 v2 = *(const float4*)(xp + 8);
            const float4 v3 = *(const float4*)(xp + 12);
            s0 = cvt8(v0, v1); s1 = cvt8(v2, v3);
        } else {
            short8 z = {}; s0 = z; s1 = z;
        }
        *(short8*)&lt[rrow][rpart * 16 + 0] = s0;
        *(short8*)&lt[rrow][rpart * 16 + 8] = s1;
        __syncthreads();
        #pragma unroll
        for (int ks = 0; ks < 2; ++ks) {
            const short8 v = *(const short8*)&lt[mi * 16 + fr][ks * 32 + fq * 8];
            *(short8*)(outp + (((kt * 2 + ks) * 4 + mi) * 4 + fq) * 128 + fr * 8) = v;
        }
        return;
    } else if (b < NB_ZERO + NB_CVTX + 16) {
        // ---- W1F[nblk16][kt8][ks2][fq4][fr16][8] ----
        const int nblk = b - NB_ZERO - NB_CVTX;
        const int fr = t & 15, fq = (t >> 4) & 3, ks = (t >> 6) & 1, kh = t >> 7;
        const int n = nblk * 16 + fr;
        #pragma unroll
        for (int k4 = 0; k4 < 4; ++k4) {
            const int kt = k4 * 2 + kh;
            const int k0 = kt * 64 + ks * 32 + fq * 8;
            unsigned short o[8];
            #pragma unroll
            for (int j = 0; j < 8; ++j) o[j] = f2b(W1[(size_t)(k0 + j) * H_FT + n]);
            *(short8*)(W1F + ((((size_t)nblk * 8 + kt) * 2 + ks) * 4 + fq) * 128 + fr * 8)
                = *(const short8*)o;
        }
    } else {
        // ---- W2F[nblk3][ks8][fq4][fr16][8] (cols 40..47 zero) ----
        const int nblk = b - NB_ZERO - NB_CVTX - 16;
        const int fr = t & 15, fq = (t >> 4) & 3, ksq = (t >> 6) & 3;
        const int n = nblk * 16 + fr;
        #pragma unroll
        for (int i = 0; i < 2; ++i) {
            const int ks = i * 4 + ksq;
            const int k0 = ks * 32 + fq * 8;
            unsigned short o[8];
            #pragma unroll
            for (int j = 0; j < 8; ++j)
                o[j] = (n < OUT_FT) ? f2b(W2[(size_t)(k0 + j) * OUT_FT + n]) : 0;
            *(short8*)(W2F + (((size_t)nblk * 8 + ks) * 4 + fq) * 128 + fr * 8)
                = *(const short8*)o;
        }
    }
}

// ===== prepB: scatter (3128 slots) : gemm1 (782), 4:1 interleave ============
// Scatter (drain-bound, VALU ~8%) hides gemm1's MFMA work.  NOTE: the 33KB
// LDS block (allocated by all blocks) throttles scatter concurrency to ~4
// blocks/CU, which empirically MINIMIZES pk write amplification (r22 showed
// 8.4KB LDS -> more concurrent scatter -> L2 thrash -> 172MB writes, +29us).
__global__ __launch_bounds__(256) void prepB_k(const int* __restrict__ src,
                                               const int* __restrict__ dst,
                                               const float* __restrict__ w,
                                               int* __restrict__ cnt,
                                               unsigned int* __restrict__ pk,
                                               const unsigned short* __restrict__ XB,
                                               const unsigned short* __restrict__ W1F,
                                               const float* __restrict__ bias,
                                               unsigned short* __restrict__ C) {
    __shared__ unsigned short ldsC[64][260];         // gemm1 epilogue only
    const int b = blockIdx.x;
    const int t = threadIdx.x;
    const int q = b / 5, r = b - q * 5;

    if (r < 4) {
        // ---- edge scatter (block-equivalent si = q*4+r) ----
        const int e = (q * 4 + r) * 256 + t;
        if (e < N_EDGES) {
            const int d = dst[e];
            const int pos = atomicAdd(&cnt[d], 1);
            if (pos < CAP) {
                pk[(size_t)d * CAP + pos] =
                    ((unsigned int)f2b(w[e]) << 16) | (unsigned int)src[e];
            }
        }
        return;
    }

    // ---- gemm1: LDS-free MFMA compute, coalesced fragment loads ----
    const int bid  = q;                              // 0..781
    const int lane = t & 63;
    const int wid  = t >> 6;
    const int m0   = bid * 64;
    const int fr   = lane & 15;
    const int fq   = lane >> 4;

    f32x4 acc[4][4] = {};
    const unsigned short* ap = XB + (size_t)bid * 32768 + lane * 8;
    const unsigned short* bp = W1F + ((size_t)wid * 4 * 8 * 2 * 64 + lane) * 8;

    #pragma unroll 2
    for (int kt = 0; kt < 8; ++kt) {
        short8 afr[8], bfr[8];
        #pragma unroll
        for (int f = 0; f < 8; ++f) {                // f = ks*4+mi
            const int mi = f & 3, ks = f >> 2;
            afr[f] = *(const short8*)(ap + ((kt * 2 + ks) * 4 + mi) * 512);
        }
        #pragma unroll
        for (int f = 0; f < 8; ++f) {                // f = ni*2+ks
            const int ni = f >> 1, ks = f & 1;
            bfr[f] = *(const short8*)(bp + ((size_t)(ni * 8 + kt) * 2 + ks) * 512);
        }
        #pragma unroll
        for (int ks = 0; ks < 2; ++ks)
            #pragma unroll
            for (int mi = 0; mi < 4; ++mi)
                #pragma unroll
                for (int ni = 0; ni < 4; ++ni)
                    acc[mi][ni] = __builtin_amdgcn_mfma_f32_16x16x32_bf16(
                        afr[ks * 4 + mi], bfr[ni * 2 + ks], acc[mi][ni], 0, 0, 0);
    }

    #pragma unroll
    for (int ni = 0; ni < 4; ++ni) {
        const int col = wid * 64 + ni * 16 + fr;
        const float bv = bias[col];
        #pragma unroll
        for (int mi = 0; mi < 4; ++mi)
            #pragma unroll
            for (int j = 0; j < 4; ++j)
                ldsC[mi * 16 + fq * 4 + j][col] = f2b(acc[mi][ni][j] + bv);
    }
    __syncthreads();
    const int row  = t >> 2;
    const int part = t & 3;
    unsigned short* cp = C + (size_t)(m0 + row) * H_FT;
    #pragma unroll
    for (int i = 0; i < 8; ++i) {
        const int c0 = part * 8 + i * 32;
        *(short8*)(cp + c0) = *(const short8*)&ldsC[row][c0];
    }
}

// ========== SpMM1 gather: 8 edges in flight (4-deep per 32-lane half) =======
__global__ __launch_bounds__(256) void spmm1_g(const int* __restrict__ cnt,
                                               const unsigned int* __restrict__ pk,
                                               const unsigned short* __restrict__ sup,
                                               unsigned short* __restrict__ hout) {
    const int m = blockIdx.x * 4 + (threadIdx.x >> 6);
    const int lane = threadIdx.x & 63;
    const int half = lane >> 5;                  // 0: even edges, 1: odd edges
    const int fl   = lane & 31;                  // feature lane: 8 bf16 each
    float aA[8] = {}, aB[8] = {}, aC[8] = {}, aD[8] = {};
    const int e = min(cnt[m], CAP);
    const unsigned int* base = pk + (size_t)m * CAP;
    int i = half;
    for (; i + 6 < e; i += 8) {                  // 4 edges per half in flight
        const unsigned int u0 = base[i], u1 = base[i + 2], u2 = base[i + 4], u3 = base[i + 6];
        const ushort8 v0 = *(const ushort8*)(sup + (size_t)(u0 & 0xFFFF) * H_FT + fl * 8);
        const ushort8 v1 = *(const ushort8*)(sup + (size_t)(u1 & 0xFFFF) * H_FT + fl * 8);
        const ushort8 v2 = *(const ushort8*)(sup + (size_t)(u2 & 0xFFFF) * H_FT + fl * 8);
        const ushort8 v3 = *(const ushort8*)(sup + (size_t)(u3 & 0xFFFF) * H_FT + fl * 8);
        const float w0 = b2f((unsigned short)(u0 >> 16));
        const float w1 = b2f((unsigned short)(u1 >> 16));
        const float w2 = b2f((unsigned short)(u2 >> 16));
        const float w3 = b2f((unsigned short)(u3 >> 16));
        #pragma unroll
        for (int j = 0; j < 8; ++j) {
            aA[j] += b2f(v0[j]) * w0;
            aB[j] += b2f(v1[j]) * w1;
            aC[j] += b2f(v2[j]) * w2;
            aD[j] += b2f(v3[j]) * w3;
        }
    }
    for (; i + 2 < e; i += 4) {                  // 2 edges per half
        const unsigned int u0 = base[i], u1 = base[i + 2];
        const ushort8 v0 = *(const ushort8*)(sup + (size_t)(u0 & 0xFFFF) * H_FT + fl * 8);
        const ushort8 v1 = *(const ushort8*)(sup + (size_t)(u1 & 0xFFFF) * H_FT + fl * 8);
        const float w0 = b2f((unsigned short)(u0 >> 16));
        const float w1 = b2f((unsigned short)(u1 >> 16));
        #pragma unroll
        for (int j = 0; j < 8; ++j) {
            aA[j] += b2f(v0[j]) * w0;
            aB[j] += b2f(v1[j]) * w1;
        }
    }
    for (; i < e; i += 2) {
        const unsigned int u = base[i];
        const ushort8 v = *(const ushort8*)(sup + (size_t)(u & 0xFFFF) * H_FT + fl * 8);
        const float w = b2f((unsigned short)(u >> 16));
        #pragma unroll
        for (int j = 0; j < 8; ++j) aA[j] += b2f(v[j]) * w;
    }
    ushort8 r;
    #pragma unroll
    for (int j = 0; j < 8; ++j) {
        float a = (aA[j] + aB[j]) + (aC[j] + aD[j]);
        a += __shfl_xor(a, 32);                  // even-half + odd-half
        r[j] = f2b(fmaxf(a, 0.f));
    }
    if (half == 0)
        *(ushort8*)(hout + (size_t)m * H_FT + fl * 8) = r;
}

// ======= GEMM2 (MFMA): sup2[M,40] = hb[M,256] @ W2F + b2  (bf16 out) ========
__global__ __launch_bounds__(256) void gemm2_mfma(const unsigned short* __restrict__ hb,
                                                  const unsigned short* __restrict__ W2F,
                                                  const float* __restrict__ b2,
                                                  unsigned short* __restrict__ sup2) {
    const int t = threadIdx.x;
    const int lane = t & 63;
    const int wid = t >> 6;
    const int fr = lane & 15;
    const int fq = lane >> 4;
    const int row = blockIdx.x * 64 + wid * 16 + fr;
    const int rl = (row < N_NODES) ? row : (N_NODES - 1);

    f32x4 acc[3] = {};
    const unsigned short* ap = hb + (size_t)rl * H_FT + fq * 8;
    #pragma unroll
    for (int ks = 0; ks < 8; ++ks) {
        const short8 a = *(const short8*)(ap + ks * 32);
        #pragma unroll
        for (int ni = 0; ni < 3; ++ni) {
            const short8 b = *(const short8*)(W2F +
                (((size_t)ni * 8 + ks) * 64 + lane) * 8);
            acc[ni] = __builtin_amdgcn_mfma_f32_16x16x32_bf16(a, b, acc[ni], 0, 0, 0);
        }
    }
    #pragma unroll
    for (int ni = 0; ni < 3; ++ni) {
        const int col = ni * 16 + fr;
        if (col >= OUT_FT) continue;
        const float bv = b2[col];
        #pragma unroll
        for (int j = 0; j < 4; ++j) {
            const int r = blockIdx.x * 64 + wid * 16 + fq * 4 + j;
            if (r < N_NODES)
                sup2[(size_t)r * OUT_FT + col] = f2b(acc[ni][j] + bv);
        }
    }
}

// ===== SpMM2 + relu + log_softmax fused (bf16 gather, 8-deep) ===============
__global__ __launch_bounds__(256) void spmm2lsm_k(const int* __restrict__ cnt,
                                                  const unsigned int* __restrict__ pk,
                                                  const unsigned short* __restrict__ sup2,
                                                  float* __restrict__ out) {
    const int m = blockIdx.x * 4 + (threadIdx.x >> 6);
    const int lane = threadIdx.x & 63;
    const int f = (lane < OUT_FT) ? lane : 0;
    float a0 = 0.f, a1 = 0.f, a2 = 0.f, a3 = 0.f;
    const int e = min(cnt[m], CAP);
    const unsigned int* base = pk + (size_t)m * CAP;
    int i = 0;
    for (; i + 8 <= e; i += 8) {
        const unsigned int u0 = base[i],     u1 = base[i + 1], u2 = base[i + 2], u3 = base[i + 3];
        const unsigned int u4 = base[i + 4], u5 = base[i + 5], u6 = base[i + 6], u7 = base[i + 7];
        const float v0 = b2f(sup2[(size_t)(u0 & 0xFFFF) * OUT_FT + f]);
        const float v1 = b2f(sup2[(size_t)(u1 & 0xFFFF) * OUT_FT + f]);
        const float v2 = b2f(sup2[(size_t)(u2 & 0xFFFF) * OUT_FT + f]);
        const float v3 = b2f(sup2[(size_t)(u3 & 0xFFFF) * OUT_FT + f]);
        const float v4 = b2f(sup2[(size_t)(u4 & 0xFFFF) * OUT_FT + f]);
        const float v5 = b2f(sup2[(size_t)(u5 & 0xFFFF) * OUT_FT + f]);
        const float v6 = b2f(sup2[(size_t)(u6 & 0xFFFF) * OUT_FT + f]);
        const float v7 = b2f(sup2[(size_t)(u7 & 0xFFFF) * OUT_FT + f]);
        a0 += v0 * b2f((unsigned short)(u0 >> 16));
        a1 += v1 * b2f((unsigned short)(u1 >> 16));
        a2 += v2 * b2f((unsigned short)(u2 >> 16));
        a3 += v3 * b2f((unsigned short)(u3 >> 16));
        a0 += v4 * b2f((unsigned short)(u4 >> 16));
        a1 += v5 * b2f((unsigned short)(u5 >> 16));
        a2 += v6 * b2f((unsigned short)(u6 >> 16));
        a3 += v7 * b2f((unsigned short)(u7 >> 16));
    }
    for (; i + 4 <= e; i += 4) {
        const unsigned int u0 = base[i], u1 = base[i + 1], u2 = base[i + 2], u3 = base[i + 3];
        a0 += b2f(sup2[(size_t)(u0 & 0xFFFF) * OUT_FT + f]) * b2f((unsigned short)(u0 >> 16));
        a1 += b2f(sup2[(size_t)(u1 & 0xFFFF) * OUT_FT + f]) * b2f((unsigned short)(u1 >> 16));
        a2 += b2f(sup2[(size_t)(u2 & 0xFFFF) * OUT_FT + f]) * b2f((unsigned short)(u2 >> 16));
        a3 += b2f(sup2[(size_t)(u3 & 0xFFFF) * OUT_FT + f]) * b2f((unsigned short)(u3 >> 16));
    }
    for (; i < e; ++i) {
        const unsigned int u = base[i];
        a0 += b2f(sup2[(size_t)(u & 0xFFFF) * OUT_FT + f]) * b2f((unsigned short)(u >> 16));
    }
    const float acc = (a0 + a1) + (a2 + a3);
    const bool act = (lane < OUT_FT);
    float r = act ? fmaxf(acc, 0.f) : 0.f;
    float mx = act ? r : -INFINITY;
    #pragma unroll
    for (int o = 32; o; o >>= 1) mx = fmaxf(mx, __shfl_xor(mx, o));
    float ex = act ? expf(r - mx) : 0.f;
    #pragma unroll
    for (int o = 32; o; o >>= 1) ex += __shfl_xor(ex, o);
    if (act) out[(size_t)m * OUT_FT + lane] = r - mx - logf(ex);
}

extern "C" void kernel_launch(void* const* d_in, const int* in_sizes, int n_in,
                              void* d_out, int out_size, void* d_ws, size_t ws_size,
                              hipStream_t stream) {
    const float* x    = (const float*)d_in[0];
    const int*   esrc = (const int*)  d_in[1];
    const int*   edst = (const int*)  d_in[2];
    const float* ew   = (const float*)d_in[3];
    const float* W1   = (const float*)d_in[4];
    const float* b1   = (const float*)d_in[5];
    const float* W2   = (const float*)d_in[6];
    const float* b2   = (const float*)d_in[7];
    float* out = (float*)d_out;

    // ---- workspace layout ----
    char* p = (char*)d_ws;
    int*  cnt    = (int*)p;               p += ((N_NODES * 4 + 255) & ~255);
    unsigned int* pk = (unsigned int*)p;  p += (size_t)N_NODES * CAP * 4;
    unsigned short* w1f  = (unsigned short*)p;  p += (size_t)H_FT * IN_FT * 2;
    unsigned short* w2f  = (unsigned short*)p;  p += (size_t)48 * H_FT * 2;
    unsigned short* sup1 = (unsigned short*)p;  p += (size_t)NROWS * H_FT * 2;
    unsigned short* hb   = (unsigned short*)p;  p += (size_t)N_NODES * H_FT * 2;
    unsigned short* sup2 = (unsigned short*)p;  p += ((size_t)N_NODES * OUT_FT * 2 + 255) & ~255;
    unsigned short* xb   = (unsigned short*)p;  p += (size_t)NBLK * 32768 * 2;

    // prepA: {zero | cvtxb | W-packs};  prepB: {scatter : gemm1, 4:1}
    prepA_k<<<NB_ZERO + NB_CVTX + 16 + 3, 256, 0, stream>>>(
        x, W1, W2, cnt, xb, w1f, w2f);
    prepB_k<<<NBLK * 5, 256, 0, stream>>>(
        esrc, edst, ew, cnt, pk, xb, w1f, b1, sup1);

    // layer 1 aggregate
    spmm1_g<<<N_NODES / 4, 256, 0, stream>>>(cnt, pk, sup1, hb);

    // layer 2 (+ fused relu + log_softmax)
    gemm2_mfma<<<(N_NODES + 63) / 64, 256, 0, stream>>>(hb, w2f, b2, sup2);
    spmm2lsm_k<<<N_NODES / 4, 256, 0, stream>>>(cnt, pk, sup2, out);
}